// Round 11
// baseline (2587.551 us; speedup 1.0000x reference)
//
#include <hip/hip_runtime.h>
#include <hip/hip_bf16.h>

#define BATCH 16
#define HH 128
#define WW 128
#define NPIX (BATCH*HH*WW)   // 262144
#define KCH 256
#define DCH 128
#define TAPS 81
#define MAXTIE 32768
#define PADH 136
#define PADW 160             // 640B rows -> 64B aligned

// ---------------- prep: zero counts + tiecnt, zero-bias flag, sigmoid table ----------------
__global__ __launch_bounds__(256) void k_prep(
    const float* __restrict__ bdown, const float* __restrict__ bup,
    const float* __restrict__ gate,
    int* __restrict__ counts, int* __restrict__ tiecnt, int* __restrict__ flag,
    float* __restrict__ sig256)
{
    __shared__ float red[256];
    int t = threadIdx.x;
    counts[t] = 0;
    if (t == 0) tiecnt[0] = 0;
    sig256[t] = 1.0f / (1.0f + expf(-gate[t]));
    float m = fabsf(bup[t]);
    if (t < DCH) m = fmaxf(m, fabsf(bdown[t]));
    red[t] = m;
    __syncthreads();
    for (int s = 128; s > 0; s >>= 1) {
        if (t < s) red[t] = fmaxf(red[t], red[t + s]);
        __syncthreads();
    }
    if (t == 0) flag[0] = (red[0] == 0.0f) ? 1 : 0;
}

// ---------------- weight transpose: wT[t][ch] = wconv[ch][t] ----------------
__global__ __launch_bounds__(256) void k_wt(
    const float* __restrict__ wconv, float* __restrict__ wT)
{
    int ch = threadIdx.x;
    for (int t = blockIdx.x; t < TAPS; t += gridDim.x)
        wT[(t << 8) + ch] = wconv[ch * TAPS + t];
}

// ---------------- zero-padded input: xpad[b][yy][xx] = x[b][yy-4][xx-4] ----------------
__global__ __launch_bounds__(256) void k_pad(
    const float* __restrict__ x, float* __restrict__ xpad)
{
    int i = blockIdx.x * 256 + threadIdx.x;
    if (i >= BATCH * PADH * PADW) return;
    int b = i / (PADH * PADW);
    int rem = i - b * (PADH * PADW);
    int yy = rem / PADW, xx = rem - yy * PADW;
    float v = 0.0f;
    if (yy >= 4 && yy < HH + 4 && xx >= 4 && xx < WW + 4)
        v = x[((size_t)b << 14) + ((yy - 4) << 7) + (xx - 4)];
    xpad[i] = v;
}

// ---------------- conv 9x9 + gate + argmax: tap-major, channel-blocked ----------------
// R7-R10 lesson: the allocator pins this kernel at ~52-56 VGPR regardless of hints,
// spilling any 81-value patch (3.4x FMA floor). So keep the live set SMALL by
// construction: 16 accumulators + one streamed patch value. Per 16-channel block:
// loop t=0..80 { pxt = base[const offset] (L1-hit); acc[c] += pxt * wT[t][kb+c]
// (s_load_dwordx16, SGPR operand) }. px is re-read 16x -- 1296 VMEM, 12% of VALU
// issue, hidden. The memory clobber stops LICM from hoisting px loads back out.
__global__ __launch_bounds__(256) void k_conv(
    const float* __restrict__ xpad, const float* __restrict__ wT,
    const float* __restrict__ sig256,
    int* __restrict__ idxb, float* __restrict__ valb, float2* __restrict__ vk,
    int* __restrict__ counts, int* __restrict__ tiecnt, int* __restrict__ tielist)
{
    __shared__ int hist[KCH];
    int tid = threadIdx.x;
    hist[tid] = 0;
    __syncthreads();

    int p = blockIdx.x * 256 + tid;
    int b = p >> 14, rem = p & 16383, y = rem >> 7, xc = rem & 127;
    const float* base = xpad + ((size_t)(b * PADH + y)) * PADW + xc;  // patch top-left

    float best = -1.0f, best2 = -1.0f; int bi = 0;

#pragma unroll 1
    for (int kb = 0; kb < KCH; kb += 16) {
        asm volatile("" ::: "memory");        // block LICM of px loads across kb iters
        const float* wb = wT + kb;
        float acc[16];
#pragma unroll
        for (int c = 0; c < 16; c++) acc[c] = 0.0f;
#pragma unroll
        for (int t = 0; t < TAPS; t++) {
            float pxt = base[(t / 9) * PADW + (t % 9)];   // compile-time offset, L1-hit
            const float* wrow = wb + (t << 8);            // wave-uniform -> s_load x16
#pragma unroll
            for (int c = 0; c < 16; c++)
                acc[c] = fmaf(pxt, wrow[c], acc[c]);
        }
#pragma unroll
        for (int c = 0; c < 16; c++) {
            float a = fmaxf(acc[c], 0.0f) * sig256[kb + c];   // sig uniform -> s_load
            int ch = kb + c;
            if (a > best) { best2 = best; best = a; bi = ch; }    // strict >: first-index
            else if (a > best2) best2 = a;
        }
    }

    idxb[p] = bi;
    valb[p] = best;
    vk[p] = make_float2(best, __int_as_float(bi));
    atomicAdd(&hist[bi], 1);
    if (best - best2 < 5e-4f) {               // near-tie -> exact re-resolve pass
        int pos = atomicAdd(tiecnt, 1);
        if (pos < MAXTIE) tielist[pos] = p;
    }
    __syncthreads();
    if (hist[tid] != 0) atomicAdd(&counts[tid], hist[tid]);
}

// ---------------- exact re-resolve for flagged pixels (one wave per pixel) ----------------
// Exact numpy-mirror f32: per channel serial t=0..80, separate mul+add rounding.
__global__ __launch_bounds__(256) void k_tie(
    const float* __restrict__ x, const float* __restrict__ wconv,
    const float* __restrict__ gate,
    const int* __restrict__ tiecnt, const int* __restrict__ tielist,
    int* __restrict__ idxb, float* __restrict__ valb, float2* __restrict__ vk,
    int* __restrict__ counts)
{
    int gw = (blockIdx.x * 256 + threadIdx.x) >> 6;
    int lane = threadIdx.x & 63;
    int nw = (gridDim.x * 256) >> 6;
    int n = tiecnt[0]; if (n > MAXTIE) n = MAXTIE;

    for (int it = gw; it < n; it += nw) {
        int pg = tielist[it];
        int b = pg >> 14, rem = pg & 16383, y = rem >> 7, xc = rem & 127;
        const float* xb = x + ((size_t)b << 14);
        float px[TAPS];
#pragma unroll
        for (int i = 0; i < 9; i++) {
#pragma unroll
            for (int j = 0; j < 9; j++) {
                int yy = y + i - 4, xx = xc + j - 4;
                px[i*9+j] = (yy >= 0 && yy < HH && xx >= 0 && xx < WW) ? xb[(yy<<7)+xx] : 0.0f;
            }
        }
        float m1 = -1.0f; int i1 = 1000;
#pragma unroll
        for (int c = 0; c < 4; c++) {
            int chh = (lane << 2) + c;
            const float* wk = wconv + chh * TAPS;
            float a = 0.0f;
#pragma unroll
            for (int t = 0; t < TAPS; t++)
                a = __fadd_rn(a, __fmul_rn(px[t], wk[t]));
            float sgc = 1.0f / (1.0f + expf(-gate[chh]));
            float v = __fmul_rn(fmaxf(a, 0.0f), sgc);
            if (v > m1) { m1 = v; i1 = chh; }
        }
#pragma unroll
        for (int s = 1; s < 64; s <<= 1) {
            float om = __shfl_xor(m1, s, 64);
            int   oi = __shfl_xor(i1, s, 64);
            if (om > m1 || (om == m1 && oi < i1)) { m1 = om; i1 = oi; }
        }
        if (lane == 0) {
            int old = idxb[pg];
            if (old != i1) { atomicSub(&counts[old], 1); atomicAdd(&counts[i1], 1); }
            idxb[pg] = i1;
            valb[pg] = m1;
            vk[pg] = make_float2(m1, __int_as_float(i1));
        }
    }
}

// ---------------- usage EMA (f64, exact +1e-6 denominator) ----------------
__global__ __launch_bounds__(256) void k_usage(
    const int* __restrict__ counts, const float* __restrict__ ema,
    float* __restrict__ out_usage)
{
    int k = threadIdx.x;
    double pfrac = (double)counts[k] / (262144.0 + 1e-6);
    out_usage[k] = (float)((double)ema[k] * 0.99 + pfrac * 0.01);
}

// ---------------- tables: M = wup·relu(wdown); G[t][j] = sum_k relu(M[k,j])·wconv[k,80-t] ----------------
__global__ __launch_bounds__(256) void k_tables(
    const float* __restrict__ wdown, const float* __restrict__ wup,
    const float* __restrict__ wconv, float* __restrict__ G)
{
    int j = blockIdx.x;
    int k = threadIdx.x;
    __shared__ float wd[DCH];
    __shared__ float mrelu[KCH];
    if (k < DCH) wd[k] = fmaxf(wdown[(k << 8) + j], 0.0f);
    __syncthreads();
    const float* wr = wup + (k << 7);
    double acc = 0.0;
    for (int d = 0; d < DCH; d++) acc += (double)wr[d] * (double)wd[d];
    mrelu[k] = fmaxf((float)acc, 0.0f);
    __syncthreads();
    if (k < TAPS) {
        double g = 0.0;
        for (int kk = 0; kk < KCH; kk++)
            g += (double)mrelu[kk] * (double)wconv[kk * TAPS + 80 - k];
        G[(k << 8) + j] = (float)g;   // layout [t][j]
    }
}

// ---------------- fast reconstruction: x_hat[p] = sum_t v[n_t]·G[t, kk[n_t]] ----------------
__global__ __launch_bounds__(256) void k_recon(
    const int* __restrict__ flag, const float2* __restrict__ vk,
    const float* __restrict__ G, float* __restrict__ out)
{
    if (flag[0] == 0) return;
    __shared__ float2 tile[24][25];
    int lx = threadIdx.x & 15, ly = threadIdx.x >> 4;
    int x0 = blockIdx.x << 4, y0 = blockIdx.y << 4;
    int b = blockIdx.z;
    const float2* vkb = vk + ((size_t)b << 14);
    for (int i = threadIdx.x; i < 576; i += 256) {
        int r = i / 24, c = i - r * 24;
        int gy = y0 + r - 4, gx = x0 + c - 4;
        float2 e = make_float2(0.0f, 0.0f);
        if (gy >= 0 && gy < HH && gx >= 0 && gx < WW) e = vkb[(gy << 7) + gx];
        tile[r][c] = e;
    }
    __syncthreads();
    float acc = 0.0f;
#pragma unroll
    for (int i = 0; i < 9; i++)
#pragma unroll
        for (int jj = 0; jj < 9; jj++) {
            float2 e = tile[ly + i][lx + jj];
            int kn = __float_as_int(e.y);
            acc = fmaf(e.x, G[((i * 9 + jj) << 8) + kn], acc);
        }
    out[((size_t)b << 14) + ((y0 + ly) << 7) + (x0 + lx)] = acc;
}

// ---------------- storage helpers + generic fallback (nonzero biases) ----------------
template<typename T> __device__ inline T to_store(float v);
template<> __device__ inline float to_store<float>(float v) { return v; }
template<> __device__ inline __hip_bfloat16 to_store<__hip_bfloat16>(float v) { return __float2bfloat16(v); }
template<typename T> __device__ inline float from_store(T v);
template<> __device__ inline float from_store<float>(float v) { return v; }
template<> __device__ inline float from_store<__hip_bfloat16>(__hip_bfloat16 v) { return __bfloat162float(v); }

template<typename T>
__global__ __launch_bounds__(256) void k_proj_fb(
    const int* __restrict__ flag,
    const int* __restrict__ idxb, const float* __restrict__ valb,
    const float* __restrict__ wdown, const float* __restrict__ bdown,
    const float* __restrict__ wup, const float* __restrict__ bup,
    const float* __restrict__ wconv,
    T* __restrict__ sbuf)
{
    if (flag[0] != 0) return;
    int p = blockIdx.x * 256 + threadIdx.x;
    int kk = idxb[p];
    float v = valb[p];

    float h[DCH];
#pragma unroll
    for (int d = 0; d < DCH; d++)
        h[d] = fmaxf(fmaf(v, wdown[(d << 8) + kk], bdown[d]), 0.0f);

    float sacc[TAPS];
#pragma unroll
    for (int t = 0; t < TAPS; t++) sacc[t] = 0.0f;

    for (int k = 0; k < KCH; k++) {
        const float* wr = wup + (k << 7);
        float a0 = bup[k], a1 = 0.f, a2 = 0.f, a3 = 0.f;
#pragma unroll
        for (int d = 0; d < DCH; d += 4) {
            a0 = fmaf(wr[d+0], h[d+0], a0);
            a1 = fmaf(wr[d+1], h[d+1], a1);
            a2 = fmaf(wr[d+2], h[d+2], a2);
            a3 = fmaf(wr[d+3], h[d+3], a3);
        }
        float a2v = fmaxf((a0 + a1) + (a2 + a3), 0.0f);
        const float* wc = wconv + k * TAPS;
#pragma unroll
        for (int t = 0; t < TAPS; t++)
            sacc[t] = fmaf(a2v, wc[80 - t], sacc[t]);
    }
#pragma unroll
    for (int t = 0; t < TAPS; t++)
        sbuf[(size_t)t * NPIX + p] = to_store<T>(sacc[t]);
}

template<typename T>
__global__ __launch_bounds__(256) void k_gather_fb(
    const int* __restrict__ flag,
    const T* __restrict__ sbuf, float* __restrict__ xhat)
{
    if (flag[0] != 0) return;
    int p = blockIdx.x * 256 + threadIdx.x;
    int b = p >> 14, rem = p & 16383, y = rem >> 7, xc = rem & 127;
    float acc = 0.0f;
#pragma unroll
    for (int i = 0; i < 9; i++) {
        int yy = y + i - 4;
        if (yy < 0 || yy >= HH) continue;
#pragma unroll
        for (int j = 0; j < 9; j++) {
            int xx = xc + j - 4;
            if (xx < 0 || xx >= WW) continue;
            int t = i * 9 + j;
            acc += from_store<T>(sbuf[(size_t)t * NPIX + (b << 14) + (yy << 7) + xx]);
        }
    }
    xhat[p] = acc;
}

extern "C" void kernel_launch(void* const* d_in, const int* in_sizes, int n_in,
                              void* d_out, int out_size, void* d_ws, size_t ws_size,
                              hipStream_t stream)
{
    const float* x     = (const float*)d_in[0];
    const float* wconv = (const float*)d_in[1];
    const float* gate  = (const float*)d_in[2];
    const float* wdown = (const float*)d_in[3];
    const float* bdown = (const float*)d_in[4];
    const float* wup   = (const float*)d_in[5];
    const float* bup   = (const float*)d_in[6];
    const float* ema   = (const float*)d_in[7];
    float* out = (float*)d_out;

    char* ws = (char*)d_ws;
    const size_t OFF_VAL  = (size_t)NPIX * 4;
    const size_t OFF_VK   = (size_t)NPIX * 8;
    const size_t OFF_CNT  = (size_t)NPIX * 16;
    const size_t OFF_ZB   = OFF_CNT + 1024;
    const size_t OFF_TC   = OFF_ZB + 1024;
    const size_t OFF_LIST = OFF_TC + 1024;
    const size_t OFF_SIG  = OFF_LIST + (size_t)MAXTIE * 4;
    const size_t OFF_WT   = OFF_SIG + 1024;
    const size_t OFF_G    = OFF_WT + (size_t)TAPS * KCH * 4;
    const size_t OFF_XP   = OFF_G + (size_t)TAPS * KCH * 4;
    const size_t OFF_SB   = OFF_XP + (size_t)BATCH * PADH * PADW * 4;

    int*    idxb   = (int*)ws;
    float*  valb   = (float*)(ws + OFF_VAL);
    float2* vk     = (float2*)(ws + OFF_VK);
    int*    counts = (int*)(ws + OFF_CNT);
    int*    zbflag = (int*)(ws + OFF_ZB);
    int*    tiecnt = (int*)(ws + OFF_TC);
    int*    tielist= (int*)(ws + OFF_LIST);
    float*  sig256 = (float*)(ws + OFF_SIG);
    float*  wT     = (float*)(ws + OFF_WT);
    float*  G      = (float*)(ws + OFF_G);
    float*  xpad   = (float*)(ws + OFF_XP);
    char*   sstart = ws + OFF_SB;

    size_t need_f32 = OFF_SB + (size_t)TAPS * NPIX * sizeof(float);

    k_prep<<<1, 256, 0, stream>>>(bdown, bup, gate, counts, tiecnt, zbflag, sig256);
    k_wt<<<81, 256, 0, stream>>>(wconv, wT);
    k_pad<<<(BATCH*PADH*PADW + 255)/256, 256, 0, stream>>>(x, xpad);
    k_conv<<<NPIX/256, 256, 0, stream>>>(xpad, wT, sig256, idxb, valb, vk,
                                         counts, tiecnt, tielist);
    k_tie<<<256, 256, 0, stream>>>(x, wconv, gate, tiecnt, tielist,
                                   idxb, valb, vk, counts);
    k_usage<<<1, 256, 0, stream>>>(counts, ema, out + NPIX);
    k_tables<<<KCH, 256, 0, stream>>>(wdown, wup, wconv, G);

    k_recon<<<dim3(8, 8, 16), 256, 0, stream>>>(zbflag, vk, G, out);

    if (ws_size >= need_f32) {
        float* sbuf = (float*)sstart;
        k_proj_fb<float><<<NPIX/256, 256, 0, stream>>>(zbflag, idxb, valb, wdown, bdown, wup, bup, wconv, sbuf);
        k_gather_fb<float><<<NPIX/256, 256, 0, stream>>>(zbflag, sbuf, out);
    } else {
        __hip_bfloat16* sbuf = (__hip_bfloat16*)sstart;
        k_proj_fb<__hip_bfloat16><<<NPIX/256, 256, 0, stream>>>(zbflag, idxb, valb, wdown, bdown, wup, bup, wconv, sbuf);
        k_gather_fb<__hip_bfloat16><<<NPIX/256, 256, 0, stream>>>(zbflag, sbuf, out);
    }
}

// Round 12
// 357.821 us; speedup vs baseline: 7.2314x; 7.2314x over previous
//
#include <hip/hip_runtime.h>
#include <hip/hip_bf16.h>

#define BATCH 16
#define HH 128
#define WW 128
#define NPIX (BATCH*HH*WW)   // 262144
#define KCH 256
#define DCH 128
#define TAPS 81
#define MAXTIE 131072
#define PADH 136
#define PADW 160             // 640B rows -> 64B aligned

typedef __attribute__((ext_vector_type(8))) short bfx8;
typedef __attribute__((ext_vector_type(4))) float fx4;

__device__ inline void split_bf16(float x, unsigned short &h, unsigned short &l) {
    unsigned u = __float_as_uint(x);
    unsigned hb = (u + 0x7FFFu + ((u >> 16) & 1u)) >> 16;
    float hf = __uint_as_float(hb << 16);
    float lf = x - hf;
    unsigned u2 = __float_as_uint(lf);
    unsigned lb = (u2 + 0x7FFFu + ((u2 >> 16) & 1u)) >> 16;
    h = (unsigned short)hb; l = (unsigned short)lb;
}

// ---------------- prep: zero counters, ok=1, zero-bias flag, sigmoid table ----------------
__global__ __launch_bounds__(256) void k_prep(
    const float* __restrict__ bdown, const float* __restrict__ bup,
    const float* __restrict__ gate,
    int* __restrict__ counts0, int* __restrict__ counts1,
    int* __restrict__ tiecnt0, int* __restrict__ tiecnt1,
    int* __restrict__ okflag, int* __restrict__ zbflag,
    float* __restrict__ sig256)
{
    __shared__ float red[256];
    int t = threadIdx.x;
    counts0[t] = 0; counts1[t] = 0;
    if (t == 0) { tiecnt0[0] = 0; tiecnt1[0] = 0; okflag[0] = 1; }
    sig256[t] = 1.0f / (1.0f + expf(-gate[t]));
    float m = fabsf(bup[t]);
    if (t < DCH) m = fmaxf(m, fabsf(bdown[t]));
    red[t] = m;
    __syncthreads();
    for (int s = 128; s > 0; s >>= 1) {
        if (t < s) red[t] = fmaxf(red[t], red[t + s]);
        __syncthreads();
    }
    if (t == 0) zbflag[0] = (red[0] == 0.0f) ? 1 : 0;
}

// ---------------- B-fragment prep: w -> bf16 hi/lo in MFMA fragment layout ----------------
// Bfrag[ks][nt][lane][j] = w[ch = nt*16 + (lane&15)][t = ks*32 + (lane>>4)*8 + j], 0 if t>80
__global__ __launch_bounds__(256) void k_wprep(
    const float* __restrict__ wconv,
    unsigned short* __restrict__ Bh, unsigned short* __restrict__ Bl)
{
    int i = blockIdx.x * 256 + threadIdx.x;
    if (i >= 3 * 16 * 64 * 8) return;
    int j = i & 7, lane = (i >> 3) & 63, nt = (i >> 9) & 15, ks = i >> 13;
    int ch = nt * 16 + (lane & 15);
    int t = ks * 32 + ((lane >> 4) & 3) * 8 + j;
    float w = (t < TAPS) ? wconv[ch * TAPS + t] : 0.0f;
    unsigned short h, l; split_bf16(w, h, l);
    Bh[i] = h; Bl[i] = l;
}

// ---------------- zero-padded input: xpad[b][yy][xx] = x[b][yy-4][xx-4] ----------------
__global__ __launch_bounds__(256) void k_pad(
    const float* __restrict__ x, float* __restrict__ xpad)
{
    int i = blockIdx.x * 256 + threadIdx.x;
    if (i >= BATCH * PADH * PADW) return;
    int b = i / (PADH * PADW);
    int rem = i - b * (PADH * PADW);
    int yy = rem / PADW, xx = rem - yy * PADW;
    float v = 0.0f;
    if (yy >= 4 && yy < HH + 4 && xx >= 4 && xx < WW + 4)
        v = x[((size_t)b << 14) + ((yy - 4) << 7) + (xx - 4)];
    xpad[i] = v;
}

// ---------------- MFMA conv: split-bf16, D[pixel][ch] = A(px)·B(w) ----------------
// A-frag: lane l reg j -> A[m = l&15][k = (l>>4)*8 + j]; B-frag: B[k][n = l&15];
// D: row m = (l>>4)*4 + r, col n = l&15 (m89-verified). 3 MFMA passes per tile:
// xh*wh + xh*wl + xl*wh (err <= ~1.2e-3 worst, tie thr 5e-3, k_tie exact-resolves).
// Block: 256 thr = 4 waves; wave = 32 pixels (2 M-frags); block = 128 px = 1 row.
__global__ __launch_bounds__(256) void k_conv_mfma(
    const float* __restrict__ xpad,
    const unsigned short* __restrict__ Bh, const unsigned short* __restrict__ Bl,
    const float* __restrict__ sig256,
    int* __restrict__ idxb, float* __restrict__ valb, float2* __restrict__ vk,
    int* __restrict__ counts0, int* __restrict__ tiecnt0, int* __restrict__ tielist0)
{
    __shared__ int hist[KCH];
    int tid = threadIdx.x;
    hist[tid] = 0;
    __syncthreads();

    int lane = tid & 63, w = tid >> 6;
    int c16 = lane & 15, g = lane >> 4;
    int p0 = blockIdx.x * 128;               // start pixel of this row-block
    int b = p0 >> 14, y = (p0 >> 7) & 127;
    int x0w = w * 32;
    const float* xrow0 = xpad + (size_t)(b * PADH + y) * PADW;

    float sigv[16];
#pragma unroll
    for (int nt = 0; nt < 16; nt++) sigv[nt] = sig256[nt * 16 + c16];

    fx4 acc[2][16];
#pragma unroll
    for (int mf = 0; mf < 2; mf++)
#pragma unroll
        for (int nt = 0; nt < 16; nt++)
            acc[mf][nt] = (fx4){0.f, 0.f, 0.f, 0.f};

#pragma unroll
    for (int ks = 0; ks < 3; ks++) {
        bfx8 ah[2], al[2];
#pragma unroll
        for (int mf = 0; mf < 2; mf++) {
#pragma unroll
            for (int j = 0; j < 8; j++) {
                int t = ks * 32 + g * 8 + j;
                float xv = 0.0f;
                if (t < TAPS) {
                    int ti = (t * 57) >> 9;          // t/9 exact for t<96
                    int tj = t - ti * 9;
                    xv = xrow0[ti * PADW + x0w + mf * 16 + c16 + tj];
                }
                unsigned short hb, lb; split_bf16(xv, hb, lb);
                ah[mf][j] = (short)hb; al[mf][j] = (short)lb;
            }
        }
#pragma unroll
        for (int nt = 0; nt < 16; nt++) {
            bfx8 bh = *(const bfx8*)(Bh + (((ks * 16 + nt) * 64 + lane) << 3));
            bfx8 bl = *(const bfx8*)(Bl + (((ks * 16 + nt) * 64 + lane) << 3));
#pragma unroll
            for (int mf = 0; mf < 2; mf++) {
                acc[mf][nt] = __builtin_amdgcn_mfma_f32_16x16x32_bf16(ah[mf], bh, acc[mf][nt], 0, 0, 0);
                acc[mf][nt] = __builtin_amdgcn_mfma_f32_16x16x32_bf16(ah[mf], bl, acc[mf][nt], 0, 0, 0);
                acc[mf][nt] = __builtin_amdgcn_mfma_f32_16x16x32_bf16(al[mf], bh, acc[mf][nt], 0, 0, 0);
            }
        }
    }

    // epilogue: per (mf, r) each 16-lane group owns pixel m = g*4 + r
#pragma unroll
    for (int mf = 0; mf < 2; mf++) {
#pragma unroll
        for (int r = 0; r < 4; r++) {
            float b1 = -1.0f, b2 = -1.0f; int i1 = 0;
#pragma unroll
            for (int nt = 0; nt < 16; nt++) {
                float a = fmaxf(acc[mf][nt][r], 0.0f) * sigv[nt];
                if (a > b1) { b2 = b1; b1 = a; i1 = nt * 16 + c16; }
                else if (a > b2) b2 = a;
            }
#pragma unroll
            for (int s = 1; s < 16; s <<= 1) {
                float ob1 = __shfl_xor(b1, s, 64);
                float ob2 = __shfl_xor(b2, s, 64);
                int   oi1 = __shfl_xor(i1, s, 64);
                float nb2 = fmaxf(fminf(b1, ob1), fmaxf(b2, ob2));
                if (ob1 > b1 || (ob1 == b1 && oi1 < i1)) { b1 = ob1; i1 = oi1; }
                b2 = nb2;
            }
            if (c16 == 0) {
                int m = g * 4 + r;
                int p = p0 + x0w + mf * 16 + m;
                idxb[p] = i1;
                valb[p] = b1;
                vk[p] = make_float2(b1, __int_as_float(i1));
                atomicAdd(&hist[i1], 1);
                if (b1 - b2 < 5e-3f) {
                    int pos = atomicAdd(tiecnt0, 1);
                    if (pos < MAXTIE) tielist0[pos] = p;
                }
            }
        }
    }
    __syncthreads();
    if (hist[tid] != 0) atomicAdd(&counts0[tid], hist[tid]);
}

// ---------------- sanity check: 16 sample pixels, exact vs mfma; clears ok on fail ----------------
__global__ __launch_bounds__(256) void k_check(
    const float* __restrict__ x, const float* __restrict__ wconv,
    const float* __restrict__ gate,
    const int* __restrict__ idxb, const float* __restrict__ valb,
    int* __restrict__ okflag)
{
    int t = threadIdx.x;   // channel
    int p = (blockIdx.x * 16411 + 9173) & (NPIX - 1);
    int b = p >> 14, rem = p & 16383, y = rem >> 7, xc = rem & 127;
    const float* xb = x + ((size_t)b << 14);
    const float* wk = wconv + t * TAPS;
    float acc = 0.0f;
#pragma unroll
    for (int i = 0; i < 9; i++) {
        int yy = y + i - 4;
#pragma unroll
        for (int j = 0; j < 9; j++) {
            int xx = xc + j - 4;
            float pv = (yy >= 0 && yy < HH && xx >= 0 && xx < WW) ? xb[(yy << 7) + xx] : 0.0f;
            acc = fmaf(pv, wk[i * 9 + j], acc);
        }
    }
    float a = fmaxf(acc, 0.0f) * (1.0f / (1.0f + expf(-gate[t])));

    __shared__ float sv[256]; __shared__ int si[256];
    sv[t] = a; si[t] = t;
    __syncthreads();
    for (int s = 128; s > 0; s >>= 1) {
        if (t < s) {
            if (sv[t+s] > sv[t] || (sv[t+s] == sv[t] && si[t+s] < si[t])) { sv[t] = sv[t+s]; si[t] = si[t+s]; }
        }
        __syncthreads();
    }
    float b1 = sv[0]; int i1 = si[0];
    __syncthreads();
    sv[t] = (t == i1) ? -1e30f : a;
    __syncthreads();
    for (int s = 128; s > 0; s >>= 1) {
        if (t < s) sv[t] = fmaxf(sv[t], sv[t+s]);
        __syncthreads();
    }
    if (t == 0) {
        float b2 = sv[0];
        float vm = valb[p]; int im = idxb[p];
        bool bad = (fabsf(b1 - vm) > 3e-3f) || (im != i1 && (b1 - b2) > 2e-2f);
        if (bad) atomicExch(okflag, 0);
    }
}

// ---------------- FALLBACK conv (proven R7 kernel) — runs only if ok==0 ----------------
__global__ __launch_bounds__(256) void k_conv_fb(
    const int* __restrict__ okflag,
    const float* __restrict__ xpad, const float* __restrict__ wconv,
    const float* __restrict__ gate,
    int* __restrict__ idxb, float* __restrict__ valb, float2* __restrict__ vk,
    int* __restrict__ counts1, int* __restrict__ tiecnt1, int* __restrict__ tielist1)
{
    if (okflag[0] != 0) return;
    __shared__ float sig[KCH];
    __shared__ int hist[KCH];
    int tid = threadIdx.x;
    sig[tid] = 1.0f / (1.0f + expf(-gate[tid]));
    hist[tid] = 0;
    __syncthreads();

    int p = blockIdx.x * 256 + tid;
    int b = p >> 14, rem = p & 16383, y = rem >> 7, xc = rem & 127;
    const float* base = xpad + ((size_t)(b * PADH + y)) * PADW + xc;

    float px[TAPS];
#pragma unroll
    for (int i = 0; i < 9; i++)
#pragma unroll
        for (int j = 0; j < 9; j++)
            px[i * 9 + j] = base[i * PADW + j];

    float best = -1.0f, best2 = -1.0f; int bi = 0;
    for (int k = 0; k < KCH; k++) {
        const float* wk = wconv + k * TAPS;
        float a0 = 0.f, a1 = 0.f, a2 = 0.f, a3 = 0.f;
#pragma unroll
        for (int t = 0; t < 80; t += 4) {
            a0 = fmaf(px[t+0], wk[t+0], a0);
            a1 = fmaf(px[t+1], wk[t+1], a1);
            a2 = fmaf(px[t+2], wk[t+2], a2);
            a3 = fmaf(px[t+3], wk[t+3], a3);
        }
        a0 = fmaf(px[80], wk[80], a0);
        float z = (a0 + a1) + (a2 + a3);
        float a = fmaxf(z, 0.0f) * sig[k];
        if (a > best) { best2 = best; best = a; bi = k; }
        else if (a > best2) { best2 = a; }
    }

    idxb[p] = bi;
    valb[p] = best;
    vk[p] = make_float2(best, __int_as_float(bi));
    atomicAdd(&hist[bi], 1);
    if (best - best2 < 5e-4f) {
        int pos = atomicAdd(tiecnt1, 1);
        if (pos < MAXTIE) tielist1[pos] = p;
    }
    __syncthreads();
    if (hist[tid] != 0) atomicAdd(&counts1[tid], hist[tid]);
}

// ---------------- exact re-resolve for flagged pixels (one wave per pixel) ----------------
__global__ __launch_bounds__(256) void k_tie(
    const int* __restrict__ okflag,
    const float* __restrict__ x, const float* __restrict__ wconv,
    const float* __restrict__ gate,
    const int* __restrict__ tiecnt0, const int* __restrict__ tielist0,
    const int* __restrict__ tiecnt1, const int* __restrict__ tielist1,
    int* __restrict__ idxb, float* __restrict__ valb, float2* __restrict__ vk,
    int* __restrict__ counts0, int* __restrict__ counts1)
{
    int ok = okflag[0];
    const int* tl = ok ? tielist0 : tielist1;
    int n = ok ? tiecnt0[0] : tiecnt1[0];
    int* cts = ok ? counts0 : counts1;
    if (n > MAXTIE) n = MAXTIE;

    int gw = (blockIdx.x * 256 + threadIdx.x) >> 6;
    int lane = threadIdx.x & 63;
    int nw = (gridDim.x * 256) >> 6;

    for (int it = gw; it < n; it += nw) {
        int pg = tl[it];
        int b = pg >> 14, rem = pg & 16383, y = rem >> 7, xc = rem & 127;
        const float* xb = x + ((size_t)b << 14);
        float px[TAPS];
#pragma unroll
        for (int i = 0; i < 9; i++) {
#pragma unroll
            for (int j = 0; j < 9; j++) {
                int yy = y + i - 4, xx = xc + j - 4;
                px[i*9+j] = (yy >= 0 && yy < HH && xx >= 0 && xx < WW) ? xb[(yy<<7)+xx] : 0.0f;
            }
        }
        float m1 = -1.0f; int i1 = 1000;
#pragma unroll
        for (int c = 0; c < 4; c++) {
            int chh = (lane << 2) + c;
            const float* wk = wconv + chh * TAPS;
            float a = 0.0f;
#pragma unroll
            for (int t = 0; t < TAPS; t++)
                a = __fadd_rn(a, __fmul_rn(px[t], wk[t]));
            float sgc = 1.0f / (1.0f + expf(-gate[chh]));
            float v = __fmul_rn(fmaxf(a, 0.0f), sgc);
            if (v > m1) { m1 = v; i1 = chh; }
        }
#pragma unroll
        for (int s = 1; s < 64; s <<= 1) {
            float om = __shfl_xor(m1, s, 64);
            int   oi = __shfl_xor(i1, s, 64);
            if (om > m1 || (om == m1 && oi < i1)) { m1 = om; i1 = oi; }
        }
        if (lane == 0) {
            int old = idxb[pg];
            if (old != i1) { atomicSub(&cts[old], 1); atomicAdd(&cts[i1], 1); }
            idxb[pg] = i1;
            valb[pg] = m1;
            vk[pg] = make_float2(m1, __int_as_float(i1));
        }
    }
}

// ---------------- usage EMA (f64, exact +1e-6 denominator) ----------------
__global__ __launch_bounds__(256) void k_usage(
    const int* __restrict__ okflag,
    const int* __restrict__ counts0, const int* __restrict__ counts1,
    const float* __restrict__ ema, float* __restrict__ out_usage)
{
    int k = threadIdx.x;
    int c = okflag[0] ? counts0[k] : counts1[k];
    double pfrac = (double)c / (262144.0 + 1e-6);
    out_usage[k] = (float)((double)ema[k] * 0.99 + pfrac * 0.01);
}

// ---------------- tables: M = wup·relu(wdown); G[t][j] = sum_k relu(M[k,j])·wconv[k,80-t] ----------------
__global__ __launch_bounds__(256) void k_tables(
    const float* __restrict__ wdown, const float* __restrict__ wup,
    const float* __restrict__ wconv, float* __restrict__ G)
{
    int j = blockIdx.x;
    int k = threadIdx.x;
    __shared__ float wd[DCH];
    __shared__ float mrelu[KCH];
    if (k < DCH) wd[k] = fmaxf(wdown[(k << 8) + j], 0.0f);
    __syncthreads();
    const float* wr = wup + (k << 7);
    double acc = 0.0;
    for (int d = 0; d < DCH; d++) acc += (double)wr[d] * (double)wd[d];
    mrelu[k] = fmaxf((float)acc, 0.0f);
    __syncthreads();
    if (k < TAPS) {
        double g = 0.0;
        for (int kk = 0; kk < KCH; kk++)
            g += (double)mrelu[kk] * (double)wconv[kk * TAPS + 80 - k];
        G[(k << 8) + j] = (float)g;   // layout [t][j]
    }
}

// ---------------- fast reconstruction: x_hat[p] = sum_t v[n_t]·G[t, kk[n_t]] ----------------
__global__ __launch_bounds__(256) void k_recon(
    const int* __restrict__ flag, const float2* __restrict__ vk,
    const float* __restrict__ G, float* __restrict__ out)
{
    if (flag[0] == 0) return;
    __shared__ float2 tile[24][25];
    int lx = threadIdx.x & 15, ly = threadIdx.x >> 4;
    int x0 = blockIdx.x << 4, y0 = blockIdx.y << 4;
    int b = blockIdx.z;
    const float2* vkb = vk + ((size_t)b << 14);
    for (int i = threadIdx.x; i < 576; i += 256) {
        int r = i / 24, c = i - r * 24;
        int gy = y0 + r - 4, gx = x0 + c - 4;
        float2 e = make_float2(0.0f, 0.0f);
        if (gy >= 0 && gy < HH && gx >= 0 && gx < WW) e = vkb[(gy << 7) + gx];
        tile[r][c] = e;
    }
    __syncthreads();
    float acc = 0.0f;
#pragma unroll
    for (int i = 0; i < 9; i++)
#pragma unroll
        for (int jj = 0; jj < 9; jj++) {
            float2 e = tile[ly + i][lx + jj];
            int kn = __float_as_int(e.y);
            acc = fmaf(e.x, G[((i * 9 + jj) << 8) + kn], acc);
        }
    out[((size_t)b << 14) + ((y0 + ly) << 7) + (x0 + lx)] = acc;
}

// ---------------- storage helpers + generic fallback (nonzero biases) ----------------
template<typename T> __device__ inline T to_store(float v);
template<> __device__ inline float to_store<float>(float v) { return v; }
template<> __device__ inline __hip_bfloat16 to_store<__hip_bfloat16>(float v) { return __float2bfloat16(v); }
template<typename T> __device__ inline float from_store(T v);
template<> __device__ inline float from_store<float>(float v) { return v; }
template<> __device__ inline float from_store<__hip_bfloat16>(__hip_bfloat16 v) { return __bfloat162float(v); }

template<typename T>
__global__ __launch_bounds__(256) void k_proj_fb(
    const int* __restrict__ flag,
    const int* __restrict__ idxb, const float* __restrict__ valb,
    const float* __restrict__ wdown, const float* __restrict__ bdown,
    const float* __restrict__ wup, const float* __restrict__ bup,
    const float* __restrict__ wconv,
    T* __restrict__ sbuf)
{
    if (flag[0] != 0) return;
    int p = blockIdx.x * 256 + threadIdx.x;
    int kk = idxb[p];
    float v = valb[p];

    float h[DCH];
#pragma unroll
    for (int d = 0; d < DCH; d++)
        h[d] = fmaxf(fmaf(v, wdown[(d << 8) + kk], bdown[d]), 0.0f);

    float sacc[TAPS];
#pragma unroll
    for (int t = 0; t < TAPS; t++) sacc[t] = 0.0f;

    for (int k = 0; k < KCH; k++) {
        const float* wr = wup + (k << 7);
        float a0 = bup[k], a1 = 0.f, a2 = 0.f, a3 = 0.f;
#pragma unroll
        for (int d = 0; d < DCH; d += 4) {
            a0 = fmaf(wr[d+0], h[d+0], a0);
            a1 = fmaf(wr[d+1], h[d+1], a1);
            a2 = fmaf(wr[d+2], h[d+2], a2);
            a3 = fmaf(wr[d+3], h[d+3], a3);
        }
        float a2v = fmaxf((a0 + a1) + (a2 + a3), 0.0f);
        const float* wc = wconv + k * TAPS;
#pragma unroll
        for (int t = 0; t < TAPS; t++)
            sacc[t] = fmaf(a2v, wc[80 - t], sacc[t]);
    }
#pragma unroll
    for (int t = 0; t < TAPS; t++)
        sbuf[(size_t)t * NPIX + p] = to_store<T>(sacc[t]);
}

template<typename T>
__global__ __launch_bounds__(256) void k_gather_fb(
    const int* __restrict__ flag,
    const T* __restrict__ sbuf, float* __restrict__ xhat)
{
    if (flag[0] != 0) return;
    int p = blockIdx.x * 256 + threadIdx.x;
    int b = p >> 14, rem = p & 16383, y = rem >> 7, xc = rem & 127;
    float acc = 0.0f;
#pragma unroll
    for (int i = 0; i < 9; i++) {
        int yy = y + i - 4;
        if (yy < 0 || yy >= HH) continue;
#pragma unroll
        for (int j = 0; j < 9; j++) {
            int xx = xc + j - 4;
            if (xx < 0 || xx >= WW) continue;
            int t = i * 9 + j;
            acc += from_store<T>(sbuf[(size_t)t * NPIX + (b << 14) + (yy << 7) + xx]);
        }
    }
    xhat[p] = acc;
}

extern "C" void kernel_launch(void* const* d_in, const int* in_sizes, int n_in,
                              void* d_out, int out_size, void* d_ws, size_t ws_size,
                              hipStream_t stream)
{
    const float* x     = (const float*)d_in[0];
    const float* wconv = (const float*)d_in[1];
    const float* gate  = (const float*)d_in[2];
    const float* wdown = (const float*)d_in[3];
    const float* bdown = (const float*)d_in[4];
    const float* wup   = (const float*)d_in[5];
    const float* bup   = (const float*)d_in[6];
    const float* ema   = (const float*)d_in[7];
    float* out = (float*)d_out;

    char* ws = (char*)d_ws;
    const size_t OFF_VAL  = (size_t)NPIX * 4;
    const size_t OFF_VK   = OFF_VAL + (size_t)NPIX * 4;
    const size_t OFF_CNT0 = OFF_VK + (size_t)NPIX * 8;
    const size_t OFF_CNT1 = OFF_CNT0 + 1024;
    const size_t OFF_ZB   = OFF_CNT1 + 1024;
    const size_t OFF_OK   = OFF_ZB + 1024;
    const size_t OFF_TC0  = OFF_OK + 1024;
    const size_t OFF_TC1  = OFF_TC0 + 1024;
    const size_t OFF_SIG  = OFF_TC1 + 1024;
    const size_t OFF_L0   = OFF_SIG + 1024;
    const size_t OFF_L1   = OFF_L0 + (size_t)MAXTIE * 4;
    const size_t OFF_BH   = OFF_L1 + (size_t)MAXTIE * 4;
    const size_t OFF_BL   = OFF_BH + 3*16*64*8*2;
    const size_t OFF_G    = OFF_BL + 3*16*64*8*2;
    const size_t OFF_XP   = OFF_G + (size_t)TAPS * KCH * 4;
    const size_t OFF_SB   = OFF_XP + (size_t)BATCH * PADH * PADW * 4;

    int*    idxb   = (int*)ws;
    float*  valb   = (float*)(ws + OFF_VAL);
    float2* vk     = (float2*)(ws + OFF_VK);
    int*    counts0= (int*)(ws + OFF_CNT0);
    int*    counts1= (int*)(ws + OFF_CNT1);
    int*    zbflag = (int*)(ws + OFF_ZB);
    int*    okflag = (int*)(ws + OFF_OK);
    int*    tiecnt0= (int*)(ws + OFF_TC0);
    int*    tiecnt1= (int*)(ws + OFF_TC1);
    float*  sig256 = (float*)(ws + OFF_SIG);
    int*    tielist0 = (int*)(ws + OFF_L0);
    int*    tielist1 = (int*)(ws + OFF_L1);
    unsigned short* Bh = (unsigned short*)(ws + OFF_BH);
    unsigned short* Bl = (unsigned short*)(ws + OFF_BL);
    float*  G      = (float*)(ws + OFF_G);
    float*  xpad   = (float*)(ws + OFF_XP);
    char*   sstart = ws + OFF_SB;

    size_t need_f32 = OFF_SB + (size_t)TAPS * NPIX * sizeof(float);

    k_prep<<<1, 256, 0, stream>>>(bdown, bup, gate, counts0, counts1,
                                  tiecnt0, tiecnt1, okflag, zbflag, sig256);
    k_wprep<<<(3*16*64*8 + 255)/256, 256, 0, stream>>>(wconv, Bh, Bl);
    k_pad<<<(BATCH*PADH*PADW + 255)/256, 256, 0, stream>>>(x, xpad);
    k_conv_mfma<<<NPIX/128, 256, 0, stream>>>(xpad, Bh, Bl, sig256,
                                              idxb, valb, vk, counts0, tiecnt0, tielist0);
    k_check<<<16, 256, 0, stream>>>(x, wconv, gate, idxb, valb, okflag);
    k_conv_fb<<<NPIX/256, 256, 0, stream>>>(okflag, xpad, wconv, gate,
                                            idxb, valb, vk, counts1, tiecnt1, tielist1);
    k_tie<<<256, 256, 0, stream>>>(okflag, x, wconv, gate,
                                   tiecnt0, tielist0, tiecnt1, tielist1,
                                   idxb, valb, vk, counts0, counts1);
    k_usage<<<1, 256, 0, stream>>>(okflag, counts0, counts1, ema, out + NPIX);
    k_tables<<<KCH, 256, 0, stream>>>(wdown, wup, wconv, G);

    k_recon<<<dim3(8, 8, 16), 256, 0, stream>>>(zbflag, vk, G, out);

    if (ws_size >= need_f32) {
        float* sbuf = (float*)sstart;
        k_proj_fb<float><<<NPIX/256, 256, 0, stream>>>(zbflag, idxb, valb, wdown, bdown, wup, bup, wconv, sbuf);
        k_gather_fb<float><<<NPIX/256, 256, 0, stream>>>(zbflag, sbuf, out);
    } else {
        __hip_bfloat16* sbuf = (__hip_bfloat16*)sstart;
        k_proj_fb<__hip_bfloat16><<<NPIX/256, 256, 0, stream>>>(zbflag, idxb, valb, wdown, bdown, wup, bup, wconv, sbuf);
        k_gather_fb<__hip_bfloat16><<<NPIX/256, 256, 0, stream>>>(zbflag, sbuf, out);
    }
}

// Round 13
// 332.508 us; speedup vs baseline: 7.7819x; 1.0761x over previous
//
#include <hip/hip_runtime.h>
#include <hip/hip_bf16.h>

#define BATCH 16
#define HH 128
#define WW 128
#define NPIX (BATCH*HH*WW)   // 262144
#define KCH 256
#define DCH 128
#define TAPS 81
#define MAXTIE 131072
#define PADH 136
#define PADW 160             // 640B rows -> 64B aligned

typedef __attribute__((ext_vector_type(8))) short bfx8;
typedef __attribute__((ext_vector_type(4))) float fx4;

__device__ inline void split_bf16(float x, unsigned short &h, unsigned short &l) {
    unsigned u = __float_as_uint(x);
    unsigned hb = (u + 0x7FFFu + ((u >> 16) & 1u)) >> 16;
    float hf = __uint_as_float(hb << 16);
    float lf = x - hf;
    unsigned u2 = __float_as_uint(lf);
    unsigned lb = (u2 + 0x7FFFu + ((u2 >> 16) & 1u)) >> 16;
    h = (unsigned short)hb; l = (unsigned short)lb;
}

// ---------------- prep: zero counters, ok=1, zero-bias flag, sigmoid table ----------------
__global__ __launch_bounds__(256) void k_prep(
    const float* __restrict__ bdown, const float* __restrict__ bup,
    const float* __restrict__ gate,
    int* __restrict__ counts0, int* __restrict__ counts1,
    int* __restrict__ tiecnt0, int* __restrict__ tiecnt1,
    int* __restrict__ okflag, int* __restrict__ zbflag,
    float* __restrict__ sig256)
{
    __shared__ float red[256];
    int t = threadIdx.x;
    counts0[t] = 0; counts1[t] = 0;
    if (t == 0) { tiecnt0[0] = 0; tiecnt1[0] = 0; okflag[0] = 1; }
    sig256[t] = 1.0f / (1.0f + expf(-gate[t]));
    float m = fabsf(bup[t]);
    if (t < DCH) m = fmaxf(m, fabsf(bdown[t]));
    red[t] = m;
    __syncthreads();
    for (int s = 128; s > 0; s >>= 1) {
        if (t < s) red[t] = fmaxf(red[t], red[t + s]);
        __syncthreads();
    }
    if (t == 0) zbflag[0] = (red[0] == 0.0f) ? 1 : 0;
}

// ---------------- B-fragment prep: w -> bf16 hi/lo in MFMA fragment layout ----------------
// Bfrag[ks][nt][lane][j] = w[ch = nt*16 + (lane&15)][t = ks*32 + (lane>>4)*8 + j], 0 if t>80
__global__ __launch_bounds__(256) void k_wprep(
    const float* __restrict__ wconv,
    unsigned short* __restrict__ Bh, unsigned short* __restrict__ Bl)
{
    int i = blockIdx.x * 256 + threadIdx.x;
    if (i >= 3 * 16 * 64 * 8) return;
    int j = i & 7, lane = (i >> 3) & 63, nt = (i >> 9) & 15, ks = i >> 13;
    int ch = nt * 16 + (lane & 15);
    int t = ks * 32 + ((lane >> 4) & 3) * 8 + j;
    float w = (t < TAPS) ? wconv[ch * TAPS + t] : 0.0f;
    unsigned short h, l; split_bf16(w, h, l);
    Bh[i] = h; Bl[i] = l;
}

// ---------------- zero-padded input: xpad[b][yy][xx] = x[b][yy-4][xx-4] ----------------
__global__ __launch_bounds__(256) void k_pad(
    const float* __restrict__ x, float* __restrict__ xpad)
{
    int i = blockIdx.x * 256 + threadIdx.x;
    if (i >= BATCH * PADH * PADW) return;
    int b = i / (PADH * PADW);
    int rem = i - b * (PADH * PADW);
    int yy = rem / PADW, xx = rem - yy * PADW;
    float v = 0.0f;
    if (yy >= 4 && yy < HH + 4 && xx >= 4 && xx < WW + 4)
        v = x[((size_t)b << 14) + ((yy - 4) << 7) + (xx - 4)];
    xpad[i] = v;
}

// ---------------- MFMA conv v2: B staged in LDS (R12 was L2-latency-bound: 96
// dependent global B-loads/wave -> MfmaUtil 6%). All 4 waves share the 48 KB B
// table; inner loop reads ds_read_b128 -> pipelines with the MFMA chains. ----------------
__global__ __launch_bounds__(256) void k_conv_mfma(
    const float* __restrict__ xpad,
    const unsigned short* __restrict__ Bh, const unsigned short* __restrict__ Bl,
    const float* __restrict__ sig256,
    int* __restrict__ idxb, float* __restrict__ valb, float2* __restrict__ vk,
    int* __restrict__ counts0, int* __restrict__ tiecnt0, int* __restrict__ tielist0)
{
    __shared__ short lBh[3*16*64*8];   // 24 KB
    __shared__ short lBl[3*16*64*8];   // 24 KB
    __shared__ int hist[KCH];
    int tid = threadIdx.x;
    hist[tid] = 0;

    {   // stage B tables: 2 x 3072 int4, coalesced
        const int4* gh = (const int4*)Bh;
        const int4* gl = (const int4*)Bl;
        int4* sh = (int4*)lBh;
        int4* sl = (int4*)lBl;
#pragma unroll
        for (int i = 0; i < 12; i++) {
            sh[tid + i * 256] = gh[tid + i * 256];
            sl[tid + i * 256] = gl[tid + i * 256];
        }
    }
    __syncthreads();

    int lane = tid & 63, w = tid >> 6;
    int c16 = lane & 15, g = lane >> 4;
    int p0 = blockIdx.x * 128;               // start pixel of this row-block
    int b = p0 >> 14, y = (p0 >> 7) & 127;
    int x0w = w * 32;
    const float* xrow0 = xpad + (size_t)(b * PADH + y) * PADW;

    float sigv[16];
#pragma unroll
    for (int nt = 0; nt < 16; nt++) sigv[nt] = sig256[nt * 16 + c16];

    fx4 acc[2][16];
#pragma unroll
    for (int mf = 0; mf < 2; mf++)
#pragma unroll
        for (int nt = 0; nt < 16; nt++)
            acc[mf][nt] = (fx4){0.f, 0.f, 0.f, 0.f};

#pragma unroll
    for (int ks = 0; ks < 3; ks++) {
        bfx8 ah[2], al[2];
#pragma unroll
        for (int mf = 0; mf < 2; mf++) {
#pragma unroll
            for (int j = 0; j < 8; j++) {
                int t = ks * 32 + g * 8 + j;
                float xv = 0.0f;
                if (t < TAPS) {
                    int ti = (t * 57) >> 9;          // t/9 exact for t<96
                    int tj = t - ti * 9;
                    xv = xrow0[ti * PADW + x0w + mf * 16 + c16 + tj];
                }
                unsigned short hb, lb; split_bf16(xv, hb, lb);
                ah[mf][j] = (short)hb; al[mf][j] = (short)lb;
            }
        }
#pragma unroll
        for (int nt = 0; nt < 16; nt++) {
            bfx8 bh = *(const bfx8*)(lBh + (((ks * 16 + nt) * 64 + lane) << 3));
            bfx8 bl = *(const bfx8*)(lBl + (((ks * 16 + nt) * 64 + lane) << 3));
#pragma unroll
            for (int mf = 0; mf < 2; mf++) {
                acc[mf][nt] = __builtin_amdgcn_mfma_f32_16x16x32_bf16(ah[mf], bh, acc[mf][nt], 0, 0, 0);
                acc[mf][nt] = __builtin_amdgcn_mfma_f32_16x16x32_bf16(ah[mf], bl, acc[mf][nt], 0, 0, 0);
                acc[mf][nt] = __builtin_amdgcn_mfma_f32_16x16x32_bf16(al[mf], bh, acc[mf][nt], 0, 0, 0);
            }
        }
    }

    // epilogue: per (mf, r) each 16-lane group owns pixel m = g*4 + r
#pragma unroll
    for (int mf = 0; mf < 2; mf++) {
#pragma unroll
        for (int r = 0; r < 4; r++) {
            float b1 = -1.0f, b2 = -1.0f; int i1 = 0;
#pragma unroll
            for (int nt = 0; nt < 16; nt++) {
                float a = fmaxf(acc[mf][nt][r], 0.0f) * sigv[nt];
                if (a > b1) { b2 = b1; b1 = a; i1 = nt * 16 + c16; }
                else if (a > b2) b2 = a;
            }
#pragma unroll
            for (int s = 1; s < 16; s <<= 1) {
                float ob1 = __shfl_xor(b1, s, 64);
                float ob2 = __shfl_xor(b2, s, 64);
                int   oi1 = __shfl_xor(i1, s, 64);
                float nb2 = fmaxf(fminf(b1, ob1), fmaxf(b2, ob2));
                if (ob1 > b1 || (ob1 == b1 && oi1 < i1)) { b1 = ob1; i1 = oi1; }
                b2 = nb2;
            }
            if (c16 == 0) {
                int m = g * 4 + r;
                int p = p0 + x0w + mf * 16 + m;
                idxb[p] = i1;
                valb[p] = b1;
                vk[p] = make_float2(b1, __int_as_float(i1));
                atomicAdd(&hist[i1], 1);
                if (b1 - b2 < 5e-3f) {
                    int pos = atomicAdd(tiecnt0, 1);
                    if (pos < MAXTIE) tielist0[pos] = p;
                }
            }
        }
    }
    __syncthreads();
    if (hist[tid] != 0) atomicAdd(&counts0[tid], hist[tid]);
}

// ---------------- sanity check: 16 sample pixels, exact vs mfma; clears ok on fail ----------------
__global__ __launch_bounds__(256) void k_check(
    const float* __restrict__ x, const float* __restrict__ wconv,
    const float* __restrict__ gate,
    const int* __restrict__ idxb, const float* __restrict__ valb,
    int* __restrict__ okflag)
{
    int t = threadIdx.x;   // channel
    int p = (blockIdx.x * 16411 + 9173) & (NPIX - 1);
    int b = p >> 14, rem = p & 16383, y = rem >> 7, xc = rem & 127;
    const float* xb = x + ((size_t)b << 14);
    const float* wk = wconv + t * TAPS;
    float acc = 0.0f;
#pragma unroll
    for (int i = 0; i < 9; i++) {
        int yy = y + i - 4;
#pragma unroll
        for (int j = 0; j < 9; j++) {
            int xx = xc + j - 4;
            float pv = (yy >= 0 && yy < HH && xx >= 0 && xx < WW) ? xb[(yy << 7) + xx] : 0.0f;
            acc = fmaf(pv, wk[i * 9 + j], acc);
        }
    }
    float a = fmaxf(acc, 0.0f) * (1.0f / (1.0f + expf(-gate[t])));

    __shared__ float sv[256]; __shared__ int si[256];
    sv[t] = a; si[t] = t;
    __syncthreads();
    for (int s = 128; s > 0; s >>= 1) {
        if (t < s) {
            if (sv[t+s] > sv[t] || (sv[t+s] == sv[t] && si[t+s] < si[t])) { sv[t] = sv[t+s]; si[t] = si[t+s]; }
        }
        __syncthreads();
    }
    float b1 = sv[0]; int i1 = si[0];
    __syncthreads();
    sv[t] = (t == i1) ? -1e30f : a;
    __syncthreads();
    for (int s = 128; s > 0; s >>= 1) {
        if (t < s) sv[t] = fmaxf(sv[t], sv[t+s]);
        __syncthreads();
    }
    if (t == 0) {
        float b2 = sv[0];
        float vm = valb[p]; int im = idxb[p];
        bool bad = (fabsf(b1 - vm) > 3e-3f) || (im != i1 && (b1 - b2) > 2e-2f);
        if (bad) atomicExch(okflag, 0);
    }
}

// ---------------- FALLBACK conv (proven R7 kernel) — runs only if ok==0 ----------------
__global__ __launch_bounds__(256) void k_conv_fb(
    const int* __restrict__ okflag,
    const float* __restrict__ xpad, const float* __restrict__ wconv,
    const float* __restrict__ gate,
    int* __restrict__ idxb, float* __restrict__ valb, float2* __restrict__ vk,
    int* __restrict__ counts1, int* __restrict__ tiecnt1, int* __restrict__ tielist1)
{
    if (okflag[0] != 0) return;
    __shared__ float sig[KCH];
    __shared__ int hist[KCH];
    int tid = threadIdx.x;
    sig[tid] = 1.0f / (1.0f + expf(-gate[tid]));
    hist[tid] = 0;
    __syncthreads();

    int p = blockIdx.x * 256 + tid;
    int b = p >> 14, rem = p & 16383, y = rem >> 7, xc = rem & 127;
    const float* base = xpad + ((size_t)(b * PADH + y)) * PADW + xc;

    float px[TAPS];
#pragma unroll
    for (int i = 0; i < 9; i++)
#pragma unroll
        for (int j = 0; j < 9; j++)
            px[i * 9 + j] = base[i * PADW + j];

    float best = -1.0f, best2 = -1.0f; int bi = 0;
    for (int k = 0; k < KCH; k++) {
        const float* wk = wconv + k * TAPS;
        float a0 = 0.f, a1 = 0.f, a2 = 0.f, a3 = 0.f;
#pragma unroll
        for (int t = 0; t < 80; t += 4) {
            a0 = fmaf(px[t+0], wk[t+0], a0);
            a1 = fmaf(px[t+1], wk[t+1], a1);
            a2 = fmaf(px[t+2], wk[t+2], a2);
            a3 = fmaf(px[t+3], wk[t+3], a3);
        }
        a0 = fmaf(px[80], wk[80], a0);
        float z = (a0 + a1) + (a2 + a3);
        float a = fmaxf(z, 0.0f) * sig[k];
        if (a > best) { best2 = best; best = a; bi = k; }
        else if (a > best2) { best2 = a; }
    }

    idxb[p] = bi;
    valb[p] = best;
    vk[p] = make_float2(best, __int_as_float(bi));
    atomicAdd(&hist[bi], 1);
    if (best - best2 < 5e-4f) {
        int pos = atomicAdd(tiecnt1, 1);
        if (pos < MAXTIE) tielist1[pos] = p;
    }
    __syncthreads();
    if (hist[tid] != 0) atomicAdd(&counts1[tid], hist[tid]);
}

// ---------------- exact re-resolve for flagged pixels (one wave per pixel) ----------------
__global__ __launch_bounds__(256) void k_tie(
    const int* __restrict__ okflag,
    const float* __restrict__ x, const float* __restrict__ wconv,
    const float* __restrict__ gate,
    const int* __restrict__ tiecnt0, const int* __restrict__ tielist0,
    const int* __restrict__ tiecnt1, const int* __restrict__ tielist1,
    int* __restrict__ idxb, float* __restrict__ valb, float2* __restrict__ vk,
    int* __restrict__ counts0, int* __restrict__ counts1)
{
    int ok = okflag[0];
    const int* tl = ok ? tielist0 : tielist1;
    int n = ok ? tiecnt0[0] : tiecnt1[0];
    int* cts = ok ? counts0 : counts1;
    if (n > MAXTIE) n = MAXTIE;

    int gw = (blockIdx.x * 256 + threadIdx.x) >> 6;
    int lane = threadIdx.x & 63;
    int nw = (gridDim.x * 256) >> 6;

    for (int it = gw; it < n; it += nw) {
        int pg = tl[it];
        int b = pg >> 14, rem = pg & 16383, y = rem >> 7, xc = rem & 127;
        const float* xb = x + ((size_t)b << 14);
        float px[TAPS];
#pragma unroll
        for (int i = 0; i < 9; i++) {
#pragma unroll
            for (int j = 0; j < 9; j++) {
                int yy = y + i - 4, xx = xc + j - 4;
                px[i*9+j] = (yy >= 0 && yy < HH && xx >= 0 && xx < WW) ? xb[(yy<<7)+xx] : 0.0f;
            }
        }
        float m1 = -1.0f; int i1 = 1000;
#pragma unroll
        for (int c = 0; c < 4; c++) {
            int chh = (lane << 2) + c;
            const float* wk = wconv + chh * TAPS;
            float a = 0.0f;
#pragma unroll
            for (int t = 0; t < TAPS; t++)
                a = __fadd_rn(a, __fmul_rn(px[t], wk[t]));
            float sgc = 1.0f / (1.0f + expf(-gate[chh]));
            float v = __fmul_rn(fmaxf(a, 0.0f), sgc);
            if (v > m1) { m1 = v; i1 = chh; }
        }
#pragma unroll
        for (int s = 1; s < 64; s <<= 1) {
            float om = __shfl_xor(m1, s, 64);
            int   oi = __shfl_xor(i1, s, 64);
            if (om > m1 || (om == m1 && oi < i1)) { m1 = om; i1 = oi; }
        }
        if (lane == 0) {
            int old = idxb[pg];
            if (old != i1) { atomicSub(&cts[old], 1); atomicAdd(&cts[i1], 1); }
            idxb[pg] = i1;
            valb[pg] = m1;
            vk[pg] = make_float2(m1, __int_as_float(i1));
        }
    }
}

// ---------------- usage EMA (f64, exact +1e-6 denominator) ----------------
__global__ __launch_bounds__(256) void k_usage(
    const int* __restrict__ okflag,
    const int* __restrict__ counts0, const int* __restrict__ counts1,
    const float* __restrict__ ema, float* __restrict__ out_usage)
{
    int k = threadIdx.x;
    int c = okflag[0] ? counts0[k] : counts1[k];
    double pfrac = (double)c / (262144.0 + 1e-6);
    out_usage[k] = (float)((double)ema[k] * 0.99 + pfrac * 0.01);
}

// ---------------- tables: M = wup·relu(wdown); G[t][j] = sum_k relu(M[k,j])·wconv[k,80-t] ----------------
__global__ __launch_bounds__(256) void k_tables(
    const float* __restrict__ wdown, const float* __restrict__ wup,
    const float* __restrict__ wconv, float* __restrict__ G)
{
    int j = blockIdx.x;
    int k = threadIdx.x;
    __shared__ float wd[DCH];
    __shared__ float mrelu[KCH];
    if (k < DCH) wd[k] = fmaxf(wdown[(k << 8) + j], 0.0f);
    __syncthreads();
    const float* wr = wup + (k << 7);
    double acc = 0.0;
    for (int d = 0; d < DCH; d++) acc += (double)wr[d] * (double)wd[d];
    mrelu[k] = fmaxf((float)acc, 0.0f);
    __syncthreads();
    if (k < TAPS) {
        double g = 0.0;
        for (int kk = 0; kk < KCH; kk++)
            g += (double)mrelu[kk] * (double)wconv[kk * TAPS + 80 - k];
        G[(k << 8) + j] = (float)g;   // layout [t][j]
    }
}

// ---------------- fast reconstruction: x_hat[p] = sum_t v[n_t]·G[t, kk[n_t]] ----------------
__global__ __launch_bounds__(256) void k_recon(
    const int* __restrict__ flag, const float2* __restrict__ vk,
    const float* __restrict__ G, float* __restrict__ out)
{
    if (flag[0] == 0) return;
    __shared__ float2 tile[24][25];
    int lx = threadIdx.x & 15, ly = threadIdx.x >> 4;
    int x0 = blockIdx.x << 4, y0 = blockIdx.y << 4;
    int b = blockIdx.z;
    const float2* vkb = vk + ((size_t)b << 14);
    for (int i = threadIdx.x; i < 576; i += 256) {
        int r = i / 24, c = i - r * 24;
        int gy = y0 + r - 4, gx = x0 + c - 4;
        float2 e = make_float2(0.0f, 0.0f);
        if (gy >= 0 && gy < HH && gx >= 0 && gx < WW) e = vkb[(gy << 7) + gx];
        tile[r][c] = e;
    }
    __syncthreads();
    float acc = 0.0f;
#pragma unroll
    for (int i = 0; i < 9; i++)
#pragma unroll
        for (int jj = 0; jj < 9; jj++) {
            float2 e = tile[ly + i][lx + jj];
            int kn = __float_as_int(e.y);
            acc = fmaf(e.x, G[((i * 9 + jj) << 8) + kn], acc);
        }
    out[((size_t)b << 14) + ((y0 + ly) << 7) + (x0 + lx)] = acc;
}

// ---------------- storage helpers + generic fallback (nonzero biases) ----------------
template<typename T> __device__ inline T to_store(float v);
template<> __device__ inline float to_store<float>(float v) { return v; }
template<> __device__ inline __hip_bfloat16 to_store<__hip_bfloat16>(float v) { return __float2bfloat16(v); }
template<typename T> __device__ inline float from_store(T v);
template<> __device__ inline float from_store<float>(float v) { return v; }
template<> __device__ inline float from_store<__hip_bfloat16>(__hip_bfloat16 v) { return __bfloat162float(v); }

template<typename T>
__global__ __launch_bounds__(256) void k_proj_fb(
    const int* __restrict__ flag,
    const int* __restrict__ idxb, const float* __restrict__ valb,
    const float* __restrict__ wdown, const float* __restrict__ bdown,
    const float* __restrict__ wup, const float* __restrict__ bup,
    const float* __restrict__ wconv,
    T* __restrict__ sbuf)
{
    if (flag[0] != 0) return;
    int p = blockIdx.x * 256 + threadIdx.x;
    int kk = idxb[p];
    float v = valb[p];

    float h[DCH];
#pragma unroll
    for (int d = 0; d < DCH; d++)
        h[d] = fmaxf(fmaf(v, wdown[(d << 8) + kk], bdown[d]), 0.0f);

    float sacc[TAPS];
#pragma unroll
    for (int t = 0; t < TAPS; t++) sacc[t] = 0.0f;

    for (int k = 0; k < KCH; k++) {
        const float* wr = wup + (k << 7);
        float a0 = bup[k], a1 = 0.f, a2 = 0.f, a3 = 0.f;
#pragma unroll
        for (int d = 0; d < DCH; d += 4) {
            a0 = fmaf(wr[d+0], h[d+0], a0);
            a1 = fmaf(wr[d+1], h[d+1], a1);
            a2 = fmaf(wr[d+2], h[d+2], a2);
            a3 = fmaf(wr[d+3], h[d+3], a3);
        }
        float a2v = fmaxf((a0 + a1) + (a2 + a3), 0.0f);
        const float* wc = wconv + k * TAPS;
#pragma unroll
        for (int t = 0; t < TAPS; t++)
            sacc[t] = fmaf(a2v, wc[80 - t], sacc[t]);
    }
#pragma unroll
    for (int t = 0; t < TAPS; t++)
        sbuf[(size_t)t * NPIX + p] = to_store<T>(sacc[t]);
}

template<typename T>
__global__ __launch_bounds__(256) void k_gather_fb(
    const int* __restrict__ flag,
    const T* __restrict__ sbuf, float* __restrict__ xhat)
{
    if (flag[0] != 0) return;
    int p = blockIdx.x * 256 + threadIdx.x;
    int b = p >> 14, rem = p & 16383, y = rem >> 7, xc = rem & 127;
    float acc = 0.0f;
#pragma unroll
    for (int i = 0; i < 9; i++) {
        int yy = y + i - 4;
        if (yy < 0 || yy >= HH) continue;
#pragma unroll
        for (int j = 0; j < 9; j++) {
            int xx = xc + j - 4;
            if (xx < 0 || xx >= WW) continue;
            int t = i * 9 + j;
            acc += from_store<T>(sbuf[(size_t)t * NPIX + (b << 14) + (yy << 7) + xx]);
        }
    }
    xhat[p] = acc;
}

extern "C" void kernel_launch(void* const* d_in, const int* in_sizes, int n_in,
                              void* d_out, int out_size, void* d_ws, size_t ws_size,
                              hipStream_t stream)
{
    const float* x     = (const float*)d_in[0];
    const float* wconv = (const float*)d_in[1];
    const float* gate  = (const float*)d_in[2];
    const float* wdown = (const float*)d_in[3];
    const float* bdown = (const float*)d_in[4];
    const float* wup   = (const float*)d_in[5];
    const float* bup   = (const float*)d_in[6];
    const float* ema   = (const float*)d_in[7];
    float* out = (float*)d_out;

    char* ws = (char*)d_ws;
    const size_t OFF_VAL  = (size_t)NPIX * 4;
    const size_t OFF_VK   = OFF_VAL + (size_t)NPIX * 4;
    const size_t OFF_CNT0 = OFF_VK + (size_t)NPIX * 8;
    const size_t OFF_CNT1 = OFF_CNT0 + 1024;
    const size_t OFF_ZB   = OFF_CNT1 + 1024;
    const size_t OFF_OK   = OFF_ZB + 1024;
    const size_t OFF_TC0  = OFF_OK + 1024;
    const size_t OFF_TC1  = OFF_TC0 + 1024;
    const size_t OFF_SIG  = OFF_TC1 + 1024;
    const size_t OFF_L0   = OFF_SIG + 1024;
    const size_t OFF_L1   = OFF_L0 + (size_t)MAXTIE * 4;
    const size_t OFF_BH   = OFF_L1 + (size_t)MAXTIE * 4;
    const size_t OFF_BL   = OFF_BH + 3*16*64*8*2;
    const size_t OFF_G    = OFF_BL + 3*16*64*8*2;
    const size_t OFF_XP   = OFF_G + (size_t)TAPS * KCH * 4;
    const size_t OFF_SB   = OFF_XP + (size_t)BATCH * PADH * PADW * 4;

    int*    idxb   = (int*)ws;
    float*  valb   = (float*)(ws + OFF_VAL);
    float2* vk     = (float2*)(ws + OFF_VK);
    int*    counts0= (int*)(ws + OFF_CNT0);
    int*    counts1= (int*)(ws + OFF_CNT1);
    int*    zbflag = (int*)(ws + OFF_ZB);
    int*    okflag = (int*)(ws + OFF_OK);
    int*    tiecnt0= (int*)(ws + OFF_TC0);
    int*    tiecnt1= (int*)(ws + OFF_TC1);
    float*  sig256 = (float*)(ws + OFF_SIG);
    int*    tielist0 = (int*)(ws + OFF_L0);
    int*    tielist1 = (int*)(ws + OFF_L1);
    unsigned short* Bh = (unsigned short*)(ws + OFF_BH);
    unsigned short* Bl = (unsigned short*)(ws + OFF_BL);
    float*  G      = (float*)(ws + OFF_G);
    float*  xpad   = (float*)(ws + OFF_XP);
    char*   sstart = ws + OFF_SB;

    size_t need_f32 = OFF_SB + (size_t)TAPS * NPIX * sizeof(float);

    k_prep<<<1, 256, 0, stream>>>(bdown, bup, gate, counts0, counts1,
                                  tiecnt0, tiecnt1, okflag, zbflag, sig256);
    k_wprep<<<(3*16*64*8 + 255)/256, 256, 0, stream>>>(wconv, Bh, Bl);
    k_pad<<<(BATCH*PADH*PADW + 255)/256, 256, 0, stream>>>(x, xpad);
    k_conv_mfma<<<NPIX/128, 256, 0, stream>>>(xpad, Bh, Bl, sig256,
                                              idxb, valb, vk, counts0, tiecnt0, tielist0);
    k_check<<<16, 256, 0, stream>>>(x, wconv, gate, idxb, valb, okflag);
    k_conv_fb<<<NPIX/256, 256, 0, stream>>>(okflag, xpad, wconv, gate,
                                            idxb, valb, vk, counts1, tiecnt1, tielist1);
    k_tie<<<256, 256, 0, stream>>>(okflag, x, wconv, gate,
                                   tiecnt0, tielist0, tiecnt1, tielist1,
                                   idxb, valb, vk, counts0, counts1);
    k_usage<<<1, 256, 0, stream>>>(okflag, counts0, counts1, ema, out + NPIX);
    k_tables<<<KCH, 256, 0, stream>>>(wdown, wup, wconv, G);

    k_recon<<<dim3(8, 8, 16), 256, 0, stream>>>(zbflag, vk, G, out);

    if (ws_size >= need_f32) {
        float* sbuf = (float*)sstart;
        k_proj_fb<float><<<NPIX/256, 256, 0, stream>>>(zbflag, idxb, valb, wdown, bdown, wup, bup, wconv, sbuf);
        k_gather_fb<float><<<NPIX/256, 256, 0, stream>>>(zbflag, sbuf, out);
    } else {
        __hip_bfloat16* sbuf = (__hip_bfloat16*)sstart;
        k_proj_fb<__hip_bfloat16><<<NPIX/256, 256, 0, stream>>>(zbflag, idxb, valb, wdown, bdown, wup, bup, wconv, sbuf);
        k_gather_fb<__hip_bfloat16><<<NPIX/256, 256, 0, stream>>>(zbflag, sbuf, out);
    }
}